// Round 11
// baseline (633.411 us; speedup 1.0000x reference)
//
#include <hip/hip_runtime.h>

typedef unsigned short u16;
typedef __attribute__((ext_vector_type(4))) float f32x4;
typedef __attribute__((ext_vector_type(8))) short bf16x8;
typedef __attribute__((ext_vector_type(4))) int i32x4;

#define BB 2
#define SS 2048
#define DD 1024
#define HH 16
#define DH 64
#define KK 512

// workspace layout (bytes) — total ~77.2 MB (<= 80.1 MB proven safe in R5)
#define OFF_SCAL  ((size_t)0)                       // accbuf[2] f32, itemp[2] f32
#define OFF_WT    ((size_t)256)                     // 5 x 1024x1024 bf16 [n][k] = 10 MB
#define OFF_XB    (OFF_WT + (size_t)5*1024*1024*2)  // x bf16 [4096][1024] = 8 MB (aliases AO)
#define OFF_AO    OFF_XB                            // attn out bf16 [4096][1024] = 8 MB
#define OFF_QH    (OFF_XB + (size_t)4096*1024*2)    // Qh bf16 [4096][4096] = 32 MB
#define OFF_QN    (OFF_QH + (size_t)4096*4096*2)    // qn bf16 [B,H,S,64] = 8 MB
#define OFF_KN    (OFF_QN + (size_t)4096*1024*2)    // kn bf16 [B,H,S,64] = 8 MB
#define OFF_VT    (OFF_KN + (size_t)4096*1024*2)    // vt bf16 [B,H,64,S] = 8 MB

__device__ __forceinline__ float b2f(u16 u) { return __uint_as_float(((unsigned)u) << 16); }
__device__ __forceinline__ u16 f2b(float f) {
    unsigned u = __float_as_uint(f);
    return (u16)((u + 0x7fffu + ((u >> 16) & 1u)) >> 16);   // RNE
}

// ---------------------------------------------------------------------------
// 0) convert x fp32 -> bf16
// ---------------------------------------------------------------------------
__global__ __launch_bounds__(256) void convert_x(const float* x, u16* xb) {
    int i = (blockIdx.x * 256 + threadIdx.x) * 4;
    float4 v = *(const float4*)(x + i);
    u16 r0 = f2b(v.x), r1 = f2b(v.y), r2 = f2b(v.z), r3 = f2b(v.w);
    xb[i] = r0; xb[i + 1] = r1; xb[i + 2] = r2; xb[i + 3] = r3;
}

// ---------------------------------------------------------------------------
// 1) transpose+convert the five 1024x1024 fp32 weights into WT bf16 [n][k]
// ---------------------------------------------------------------------------
__global__ __launch_bounds__(256) void transpose_w(
        const float* Wq, const float* Wk, const float* Wv, const float* Wg, const float* Wo,
        u16* WT) {
    int z = blockIdx.z;
    const float* src = (z == 0) ? Wq : (z == 1) ? Wk : (z == 2) ? Wv : (z == 3) ? Wg : Wo;
    u16* dst = WT + (size_t)z * 1024 * 1024;
    __shared__ float tile[64][65];
    int n0 = blockIdx.x * 64, k0 = blockIdx.y * 64;
    int rbase = threadIdx.x >> 6, c = threadIdx.x & 63;
#pragma unroll
    for (int i = 0; i < 16; i++) {
        int r = i * 4 + rbase;
        tile[r][c] = src[(size_t)(k0 + r) * 1024 + n0 + c];
    }
    __syncthreads();
#pragma unroll
    for (int i = 0; i < 16; i++) {
        int r = i * 4 + rbase;
        dst[(size_t)(n0 + r) * 1024 + k0 + c] = f2b(tile[c][r]);
    }
}

// ---------------------------------------------------------------------------
// 2) adaptive temperature (fp32, validated in R5)
// ---------------------------------------------------------------------------
__global__ __launch_bounds__(256) void temp_partial(const float* x, const float* Wt,
                                                    float* accbuf) {
    int b = blockIdx.x >> 5, ch = blockIdx.x & 31;
    float a = 0.f;
    for (int si = 0; si < 64; si++) {
        int s = ch * 64 + si;
        const float* xr = x + ((size_t)(b * SS + s)) * DD;
#pragma unroll
        for (int k = 0; k < 4; k++) {
            int c = threadIdx.x + k * 256;
            a += xr[c] * Wt[c];
        }
    }
    for (int o = 32; o; o >>= 1) a += __shfl_xor(a, o);
    __shared__ float red[4];
    if ((threadIdx.x & 63) == 0) red[threadIdx.x >> 6] = a;
    __syncthreads();
    if (threadIdx.x == 0) atomicAdd(&accbuf[b], red[0] + red[1] + red[2] + red[3]);
}

__global__ void temp_final(const float* accbuf, const float* bt, float* itemp) {
    int t = threadIdx.x;
    if (t < BB) {
        float v = accbuf[t] / (float)SS + bt[0];
        float tmp = 1.f / (1.f + __expf(-v)) + 0.5f;
        itemp[t] = 1.f / tmp;
    }
}

// ---------------------------------------------------------------------------
// 3) QKVG GEMM (MFMA): xb[4096,1024] x WT(4 mats) -> Qh bf16 [4096,4096] +bias
// ---------------------------------------------------------------------------
__global__ __launch_bounds__(256) void gemm_qkvg(
        const u16* X, const u16* WT,
        const float* bq, const float* bk, const float* bv, const float* bg, u16* Qh) {
    __shared__ u16 la[64 * 40];
    __shared__ u16 lb[64 * 40];
    int tid = threadIdx.x, wid = tid >> 6, lane = tid & 63;
    int m0 = blockIdx.x * 64, n0 = blockIdx.y * 64;
    int quad = lane >> 4, ml = lane & 15;
    f32x4 acc[4];
#pragma unroll
    for (int i = 0; i < 4; i++) acc[i] = (f32x4){0.f, 0.f, 0.f, 0.f};

    int sr = tid >> 2, sg = tid & 3;
    for (int k0 = 0; k0 < 1024; k0 += 32) {
        __syncthreads();
        *(i32x4*)&la[sr * 40 + sg * 8] = *(const i32x4*)&X[(size_t)(m0 + sr) * 1024 + k0 + sg * 8];
        *(i32x4*)&lb[sr * 40 + sg * 8] = *(const i32x4*)&WT[(size_t)(n0 + sr) * 1024 + k0 + sg * 8];
        __syncthreads();
        bf16x8 a = *(const bf16x8*)&la[(wid * 16 + ml) * 40 + quad * 8];
#pragma unroll
        for (int nt = 0; nt < 4; nt++) {
            bf16x8 bfr = *(const bf16x8*)&lb[(nt * 16 + ml) * 40 + quad * 8];
            acc[nt] = __builtin_amdgcn_mfma_f32_16x16x32_bf16(a, bfr, acc[nt], 0, 0, 0);
        }
    }
#pragma unroll
    for (int nt = 0; nt < 4; nt++) {
        int col = n0 + nt * 16 + ml;
        int mat = col >> 10, bc = col & 1023;
        const float* bp = (mat == 0) ? bq : (mat == 1) ? bk : (mat == 2) ? bv : bg;
        float bias = bp[bc];
#pragma unroll
        for (int r = 0; r < 4; r++) {
            int row = m0 + wid * 16 + quad * 4 + r;
            Qh[(size_t)row * 4096 + col] = f2b(acc[nt][r] + bias);
        }
    }
}

// ---------------------------------------------------------------------------
// 4) normalize q,k -> packed qn,kn [B,H,S,64]; v -> vt [B,H,64,S] via LDS
//    transpose tile (coalesced 128B row writes — no 2B scatter).
//    block = (bh, 64-token tile); 1024 blocks x 256 threads.
// ---------------------------------------------------------------------------
__global__ __launch_bounds__(256) void norm_repack(const u16* Qh, u16* qn, u16* kn, u16* vt) {
    __shared__ u16 vtile[64][72];
    int tid = threadIdx.x, wid = tid >> 6, lane = tid & 63;
    int bh = blockIdx.x >> 5, stile = blockIdx.x & 31;
    int b = bh >> 4, h = bh & 15;
    int s0 = stile * 64;
    for (int t = 0; t < 16; t++) {
        int sl = wid * 16 + t;
        int s = s0 + sl;
        const u16* rowp = Qh + ((size_t)(b * SS + s)) * 4096 + h * 64;
        float q = b2f(rowp[lane]);
        float k = b2f(rowp[1024 + lane]);
        u16 v = rowp[2048 + lane];
        float sq = q * q, sk = k * k;
        for (int o = 32; o; o >>= 1) { sq += __shfl_xor(sq, o); sk += __shfl_xor(sk, o); }
        float qd = fmaxf(sqrtf(sq), 1e-12f), kd = fmaxf(sqrtf(sk), 1e-12f);
        size_t orow = ((size_t)bh * SS + s) * DH;
        qn[orow + lane] = f2b(q / qd);
        kn[orow + lane] = f2b(k / kd);
        vtile[lane][sl] = v;
    }
    __syncthreads();
    int dh = tid >> 2, c0 = (tid & 3) * 16;
    u16* dst = vt + ((size_t)bh * DH + dh) * SS + s0 + c0;
    *(i32x4*)dst       = *(const i32x4*)&vtile[dh][c0];
    *(i32x4*)(dst + 8) = *(const i32x4*)&vtile[dh][c0 + 8];
}

// ---------------------------------------------------------------------------
// 5) attention: 1024 threads / 16 waves per block = (b,h,16 q rows).
//    Scores: 16 waves x 8 col-chunks (direct-from-global B-frags, bf16->LDS).
//    Select: per-wave PRIVATE two-level 256-bin radix histogram (streaming —
//    3 element passes, no barriers, bank-staggered). PV: 4 dh-groups x 4
//    K-quarters; partials in LDS (aliases the dead histogram region).
// ---------------------------------------------------------------------------
#define EST 2088   // u16 stride: (EST/2)%32==20 -> b128 A-frag reads spread all 32 banks

__global__ __launch_bounds__(1024, 8) void attn_kernel(
        const u16* qn, const u16* kn, const u16* vt, const float* itemp, u16* ao) {
    __shared__ __align__(16) u16 e16[16 * EST];   // 66816 B
    __shared__ float shpv[3][16][66];             // 12672 B: hist (select) / PV partials
    __shared__ float zrow_s[16];

    int tid = threadIdx.x, wid = tid >> 6, lane = tid & 63;   // wid in [0,16)
    int quad = lane >> 4, nl = lane & 15;
    int bh = blockIdx.x >> 7, qt = blockIdx.x & 127;
    int b = bh >> 4, h = bh & 15;
    const u16* qbase = qn + ((size_t)bh * SS + qt * 16) * DH;
    const u16* kbase = kn + (size_t)bh * SS * DH;
    const u16* vbase = vt + (size_t)bh * DH * SS;
    float it = itemp[b];

    // q A-fragments: lane holds q[m=nl][k=quad*8+j (+32)]
    bf16x8 aq0 = *(const bf16x8*)(qbase + nl * DH + quad * 8);
    bf16x8 aq1 = *(const bf16x8*)(qbase + nl * DH + 32 + quad * 8);

    // ---- scores: wave wid covers cols wid*16+nl (mod 256), 8 chunks ----
#pragma unroll 4
    for (int c = 0; c < 8; c++) {
        int j = c * 256 + wid * 16 + nl;
        const u16* kr = kbase + (size_t)j * DH;
        bf16x8 b0 = *(const bf16x8*)(kr + quad * 8);
        bf16x8 b1 = *(const bf16x8*)(kr + 32 + quad * 8);
        f32x4 acc = (f32x4){0.f, 0.f, 0.f, 0.f};
        acc = __builtin_amdgcn_mfma_f32_16x16x32_bf16(aq0, b0, acc, 0, 0, 0);
        acc = __builtin_amdgcn_mfma_f32_16x16x32_bf16(aq1, b1, acc, 0, 0, 0);
#pragma unroll
        for (int r = 0; r < 4; r++) e16[(quad * 4 + r) * EST + j] = f2b(acc[r] * it);
    }
    __syncthreads();

    // ---- select: wave wid owns row wid; private 2-level radix histogram ----
    {
        int row = wid;
        unsigned* wh = (unsigned*)&shpv[0][0][0] + wid * 132;   // 128 words, staggered
        const u16* rowp = &e16[row * EST];
        wh[lane] = 0u; wh[64 + lane] = 0u;
        // level-1: histogram of key>>8 (u16-pair packed; counts <= 2048)
#pragma unroll 4
        for (int c = 0; c < 32; c++) {
            int raw = (int)rowp[c * 64 + lane];
            int key = (raw & 0x8000) ? (raw ^ 0xFFFF) : (raw | 0x8000);
            int bin = key >> 8;
            atomicAdd(&wh[bin >> 1], (bin & 1) ? 65536u : 1u);
        }
        unsigned w0 = wh[2 * lane], w1 = wh[2 * lane + 1];   // lane owns bins 4l..4l+3
        unsigned c0 = w0 & 0xFFFFu, c1 = w0 >> 16, c2 = w1 & 0xFFFFu, c3 = w1 >> 16;
        unsigned suf = c0 + c1 + c2 + c3;
#pragma unroll
        for (int o = 1; o < 64; o <<= 1) {
            unsigned t = __shfl_down(suf, o);
            suf += (lane + o < 64) ? t : 0u;
        }
        unsigned S0 = suf, S1 = suf - c0, S2 = S1 - c1, S3 = S2 - c2;
        int lb = -1;
        if (S3 >= (unsigned)KK) lb = 4 * lane + 3;
        else if (S2 >= (unsigned)KK) lb = 4 * lane + 2;
        else if (S1 >= (unsigned)KK) lb = 4 * lane + 1;
        else if (S0 >= (unsigned)KK) lb = 4 * lane;
#pragma unroll
        for (int o = 32; o; o >>= 1) { int t = __shfl_xor(lb, o); lb = (t > lb) ? t : lb; }
        int bstar = lb;
        int sel = bstar & 3;
        unsigned cb = (sel == 0) ? c0 : (sel == 1) ? c1 : (sel == 2) ? c2 : c3;
        unsigned Sb = (sel == 0) ? S0 : (sel == 1) ? S1 : (sel == 2) ? S2 : S3;
        unsigned nd2 = (unsigned)KK - (Sb - cb);            // valid on owner lane
        nd2 = (unsigned)__shfl((int)nd2, bstar >> 2);
        // level-2: histogram of key&255 within bin bstar
        wh[lane] = 0u; wh[64 + lane] = 0u;
#pragma unroll 4
        for (int c = 0; c < 32; c++) {
            int raw = (int)rowp[c * 64 + lane];
            int key = (raw & 0x8000) ? (raw ^ 0xFFFF) : (raw | 0x8000);
            if ((key >> 8) == bstar) {
                int lo = key & 255;
                atomicAdd(&wh[lo >> 1], (lo & 1) ? 65536u : 1u);
            }
        }
        w0 = wh[2 * lane]; w1 = wh[2 * lane + 1];
        c0 = w0 & 0xFFFFu; c1 = w0 >> 16; c2 = w1 & 0xFFFFu; c3 = w1 >> 16;
        suf = c0 + c1 + c2 + c3;
#pragma unroll
        for (int o = 1; o < 64; o <<= 1) {
            unsigned t = __shfl_down(suf, o);
            suf += (lane + o < 64) ? t : 0u;
        }
        S0 = suf; S1 = suf - c0; S2 = S1 - c1; S3 = S2 - c2;
        lb = -1;
        if (S3 >= nd2) lb = 4 * lane + 3;
        else if (S2 >= nd2) lb = 4 * lane + 2;
        else if (S1 >= nd2) lb = 4 * lane + 1;
        else if (S0 >= nd2) lb = 4 * lane;
#pragma unroll
        for (int o = 32; o; o >>= 1) { int t = __shfl_xor(lb, o); lb = (t > lb) ? t : lb; }
        int P = (bstar << 8) | lb;
        // exp (m=0: |s| < ~2.02, no overflow) + Z, write weights back
        float z = 0.f;
        u16* roww = &e16[row * EST];
#pragma unroll 4
        for (int c = 0; c < 32; c++) {
            int raw = (int)rowp[c * 64 + lane];
            int key = (raw & 0x8000) ? (raw ^ 0xFFFF) : (raw | 0x8000);
            float e = 0.f;
            if (key >= P) e = __expf(b2f((u16)raw));
            z += e;
            roww[c * 64 + lane] = f2b(e);
        }
#pragma unroll
        for (int o = 32; o; o >>= 1) z += __shfl_xor(z, o);
        if (lane == 0) zrow_s[row] = z;
    }
    __syncthreads();   // also fences hist region before PV-partial reuse

    // ---- PV: wave = (K-quarter kq = wid>>2, dh-group g = wid&3) ----
    f32x4 accp = (f32x4){0.f, 0.f, 0.f, 0.f};
    int kq = wid >> 2, g = wid & 3;
    int dh = g * 16 + nl;
    const u16* vrow = vbase + (size_t)dh * SS;
#pragma unroll 4
    for (int c = 0; c < 8; c++) {
        int j0 = kq * 512 + c * 64;
#pragma unroll
        for (int ks = 0; ks < 2; ks++) {
            bf16x8 a = *(const bf16x8*)&e16[nl * EST + j0 + ks * 32 + quad * 8];
            bf16x8 bfr = *(const bf16x8*)(vrow + j0 + ks * 32 + quad * 8);
            accp = __builtin_amdgcn_mfma_f32_16x16x32_bf16(a, bfr, accp, 0, 0, 0);
        }
    }
    if (kq) {
#pragma unroll
        for (int r = 0; r < 4; r++) shpv[kq - 1][quad * 4 + r][dh] = accp[r];
    }
    __syncthreads();
    if (kq == 0) {
#pragma unroll
        for (int r = 0; r < 4; r++) {
            int q = quad * 4 + r;
            float val = (accp[r] + shpv[0][q][dh] + shpv[1][q][dh] + shpv[2][q][dh]) / zrow_s[q];
            size_t row = (size_t)(b * SS + qt * 16 + q);
            ao[row * DD + h * 64 + dh] = f2b(val);
        }
    }
}

// ---------------------------------------------------------------------------
// 6) out = attn_out @ Wo + bo, highway: gate*out + (1-gate)*x -> fp32
// ---------------------------------------------------------------------------
__global__ __launch_bounds__(256) void gemm_out(
        const u16* AO, const u16* WTo, const float* bo,
        const u16* Qh, const float* x, float* out) {
    __shared__ u16 la[64 * 40];
    __shared__ u16 lb[64 * 40];
    int tid = threadIdx.x, wid = tid >> 6, lane = tid & 63;
    int m0 = blockIdx.x * 64, n0 = blockIdx.y * 64;
    int quad = lane >> 4, ml = lane & 15;
    f32x4 acc[4];
#pragma unroll
    for (int i = 0; i < 4; i++) acc[i] = (f32x4){0.f, 0.f, 0.f, 0.f};

    int sr = tid >> 2, sg = tid & 3;
    for (int k0 = 0; k0 < 1024; k0 += 32) {
        __syncthreads();
        *(i32x4*)&la[sr * 40 + sg * 8] = *(const i32x4*)&AO[(size_t)(m0 + sr) * 1024 + k0 + sg * 8];
        *(i32x4*)&lb[sr * 40 + sg * 8] = *(const i32x4*)&WTo[(size_t)(n0 + sr) * 1024 + k0 + sg * 8];
        __syncthreads();
        bf16x8 a = *(const bf16x8*)&la[(wid * 16 + ml) * 40 + quad * 8];
#pragma unroll
        for (int nt = 0; nt < 4; nt++) {
            bf16x8 bfr = *(const bf16x8*)&lb[(nt * 16 + ml) * 40 + quad * 8];
            acc[nt] = __builtin_amdgcn_mfma_f32_16x16x32_bf16(a, bfr, acc[nt], 0, 0, 0);
        }
    }
#pragma unroll
    for (int nt = 0; nt < 4; nt++) {
        int col = n0 + nt * 16 + ml;
        float bias = bo[col];
#pragma unroll
        for (int r = 0; r < 4; r++) {
            int row = m0 + wid * 16 + quad * 4 + r;
            float g = b2f(Qh[(size_t)row * 4096 + 3072 + col]);
            float gate = 1.f / (1.f + __expf(-g));
            float xv = x[(size_t)row * 1024 + col];
            float o = acc[nt][r] + bias;
            out[(size_t)row * 1024 + col] = gate * o + (1.f - gate) * xv;
        }
    }
}

// ---------------------------------------------------------------------------
extern "C" void kernel_launch(void* const* d_in, const int* in_sizes, int n_in,
                              void* d_out, int out_size, void* d_ws, size_t ws_size,
                              hipStream_t stream) {
    const float* x  = (const float*)d_in[0];
    const float* Wq = (const float*)d_in[1];
    const float* bq = (const float*)d_in[2];
    const float* Wk = (const float*)d_in[3];
    const float* bk = (const float*)d_in[4];
    const float* Wv = (const float*)d_in[5];
    const float* bv = (const float*)d_in[6];
    const float* Wo = (const float*)d_in[7];
    const float* bo = (const float*)d_in[8];
    const float* Wt = (const float*)d_in[9];
    const float* bt = (const float*)d_in[10];
    const float* Wg = (const float*)d_in[11];
    const float* bg = (const float*)d_in[12];

    char* w = (char*)d_ws;
    float* accbuf = (float*)(w + OFF_SCAL);
    float* itemp  = accbuf + 2;
    u16*   WT     = (u16*)(w + OFF_WT);
    u16*   xb     = (u16*)(w + OFF_XB);
    u16*   ao     = (u16*)(w + OFF_AO);   // aliases xb (disjoint lifetime)
    u16*   Qh     = (u16*)(w + OFF_QH);
    u16*   qn     = (u16*)(w + OFF_QN);
    u16*   kn     = (u16*)(w + OFF_KN);
    u16*   vt     = (u16*)(w + OFF_VT);

    hipMemsetAsync(accbuf, 0, 2 * sizeof(float), stream);

    convert_x<<<4096, 256, 0, stream>>>(x, xb);
    transpose_w<<<dim3(16, 16, 5), 256, 0, stream>>>(Wq, Wk, Wv, Wg, Wo, WT);
    temp_partial<<<64, 256, 0, stream>>>(x, Wt, accbuf);
    temp_final<<<1, 64, 0, stream>>>(accbuf, bt, itemp);
    gemm_qkvg<<<dim3(64, 64), 256, 0, stream>>>(xb, WT, bq, bk, bv, bg, Qh);
    norm_repack<<<1024, 256, 0, stream>>>(Qh, qn, kn, vt);
    attn_kernel<<<4096, 1024, 0, stream>>>(qn, kn, vt, itemp, ao);
    gemm_out<<<dim3(64, 16), 256, 0, stream>>>(ao, WT + (size_t)4 * 1024 * 1024, bo, Qh, x,
                                               (float*)d_out);
}